// Round 10
// baseline (312.918 us; speedup 1.0000x reference)
//
#include <hip/hip_runtime.h>

#define S_LEN 2048
#define NH 16
#define HD 64
#define DMODEL 1024

typedef __attribute__((ext_vector_type(8))) short bf16x8;
typedef __attribute__((ext_vector_type(4))) float f32x4;
typedef __attribute__((ext_vector_type(4))) unsigned int u32x4;

__device__ inline unsigned short f2bf(float f) {
  union { float f; unsigned u; } v; v.f = f;
  unsigned r = v.u + 0x7FFFu + ((v.u >> 16) & 1u);
  return (unsigned short)(r >> 16);
}

__device__ inline void async16(void* lds, const void* g) {
  __builtin_amdgcn_global_load_lds((__attribute__((address_space(1))) void*)(g),
                                   (__attribute__((address_space(3))) void*)(lds),
                                   16, 0, 0);
}

// pack two positive f32 to bf16 pair (round-half-up), low word = a
__device__ inline unsigned pkbf(float a, float b) {
  unsigned ua = __float_as_uint(a) + 0x8000u;
  unsigned ub = __float_as_uint(b) + 0x8000u;
  return (ua >> 16) | (ub & 0xFFFF0000u);
}

// ---------------- prep: fp32->bf16 casts + bias table (exp2-domain) ----------------
__global__ __launch_bounds__(256) void prep_kernel(
    const float* __restrict__ x, const float* __restrict__ emb,
    const float* __restrict__ qkv_w, const float* __restrict__ o_w,
    unsigned short* __restrict__ xb, unsigned short* __restrict__ wb,
    unsigned short* __restrict__ ob, float* __restrict__ biasg) {
  if (blockIdx.x >= 8192) {
    int h = blockIdx.x - 8192;
    for (int i = threadIdx.x; i < 4095; i += 256) {
      int rel = i - 2047;                       // rel = k - q
      int a = rel < 0 ? -rel : rel;
      int bucket;
      if (a < 8) bucket = a;
      else bucket = 8 + (a >= 12) + (a >= 16) + (a >= 23) + (a >= 32) +
                        (a >= 46) + (a >= 64) + (a >= 91);
      if (rel > 0) bucket += 16;
      biasg[h * 4096 + i] = emb[bucket * NH + h] * 1.4426950408889634f;
    }
    return;
  }
  const int NX = 2 * S_LEN * DMODEL / 4;
  const int NW = 3 * NH * HD * DMODEL / 4;
  int j = blockIdx.x * 256 + threadIdx.x;
  const float* s; unsigned short* d;
  if (j < NX)            { s = x;     d = xb; }
  else if (j < NX + NW)  { j -= NX;      s = qkv_w; d = wb; }
  else                   { j -= NX + NW; s = o_w;   d = ob; }
  float4 v = ((const float4*)s)[j];
  ushort4 p;
  p.x = f2bf(v.x); p.y = f2bf(v.y); p.z = f2bf(v.z); p.w = f2bf(v.w);
  ((ushort4*)d)[j] = p;
}

// ---------------- QKV GEMM: [4096,1024]bf16 @ [3072,1024]^T -> Q,K,Vt ----------------
__global__ __launch_bounds__(256) void qkv_gemm_kernel(
    const unsigned short* __restrict__ xb, const unsigned short* __restrict__ wb,
    unsigned short* __restrict__ Qg, unsigned short* __restrict__ Kg,
    unsigned short* __restrict__ Vtg) {
  __shared__ __align__(16) char smem[32768];
  char* As = smem;
  char* Bs = smem + 16384;
  int bid = blockIdx.x;
  int swz = (bid & 7) * 96 + (bid >> 3);
  int bm = swz / 24, bn = swz % 24;
  const int tid = threadIdx.x, lane = tid & 63, wave = tid >> 6;
  const int wr = wave >> 1, wc = wave & 1, lg = lane >> 4, li = lane & 15;
  const char* Ag = (const char*)xb;
  const char* Bg = (const char*)wb;

  f32x4 acc[4][4];
#pragma unroll
  for (int i = 0; i < 4; ++i)
#pragma unroll
    for (int j = 0; j < 4; ++j) acc[i][j] = (f32x4){0.f, 0.f, 0.f, 0.f};

  auto stage = [&](int buf, int kt) {
#pragma unroll
    for (int r = 0; r < 2; ++r) {
      int c = wave * 2 + r;
      int linear = c * 1024 + lane * 16;
      int row = linear >> 6;
      int cb = (linear & 63) ^ ((row & 3) << 4);
      async16(As + buf * 8192 + c * 1024,
              Ag + (size_t)(bm * 128 + row) * 2048 + kt * 64 + cb);
      async16(Bs + buf * 8192 + c * 1024,
              Bg + (size_t)(bn * 128 + row) * 2048 + kt * 64 + cb);
    }
  };

  stage(0, 0);
  __syncthreads();
  for (int kt = 0; kt < 32; ++kt) {
    int cur = kt & 1;
    if (kt < 31) stage(cur ^ 1, kt + 1);
    const char* Ab = As + cur * 8192;
    const char* Bb = Bs + cur * 8192;
    bf16x8 af[4], bfr[4];
#pragma unroll
    for (int i = 0; i < 4; ++i) {
      int ra = wr * 64 + i * 16 + li;
      af[i] = *(const bf16x8*)(Ab + ra * 64 + ((lg * 16) ^ ((ra & 3) << 4)));
      int rb = wc * 64 + i * 16 + li;
      bfr[i] = *(const bf16x8*)(Bb + rb * 64 + ((lg * 16) ^ ((rb & 3) << 4)));
    }
#pragma unroll
    for (int i = 0; i < 4; ++i)
#pragma unroll
      for (int j = 0; j < 4; ++j)
        acc[i][j] = __builtin_amdgcn_mfma_f32_16x16x32_bf16(af[i], bfr[j], acc[i][j], 0, 0, 0);
    __syncthreads();
  }

  int n0 = bn * 128 + wc * 64;
  int which = n0 >> 10;
  int h = (n0 >> 6) & 15;
  if (which < 2) {
    unsigned short* dst = (which == 0) ? Qg : Kg;
    float scl = (which == 0) ? 0.18033688011112042f : 1.0f;
#pragma unroll
    for (int i = 0; i < 4; ++i)
#pragma unroll
      for (int j = 0; j < 4; ++j)
#pragma unroll
        for (int r = 0; r < 4; ++r) {
          int mr = bm * 128 + wr * 64 + i * 16 + lg * 4 + r;
          int b = mr >> 11, sIdx = mr & 2047;
          int d = j * 16 + li;
          dst[(((size_t)(b * NH + h)) * S_LEN + sIdx) * HD + d] = f2bf(acc[i][j][r] * scl);
        }
  } else {
    char* T = smem + wave * 8192;
#pragma unroll
    for (int i = 0; i < 4; ++i)
#pragma unroll
      for (int j = 0; j < 4; ++j)
#pragma unroll
        for (int r = 0; r < 4; ++r) {
          int sl = i * 16 + lg * 4 + r;
          int dd = j * 16 + li;
          *(unsigned short*)(T + dd * 128 + ((sl * 2) ^ ((dd & 7) << 4))) = f2bf(acc[i][j][r]);
        }
    int m0 = bm * 128 + wr * 64;
    int b = m0 >> 11, s0 = m0 & 2047;
#pragma unroll
    for (int r2 = 0; r2 < 8; ++r2) {
      int linear = r2 * 1024 + lane * 16;
      int dd = linear >> 7;
      int ts = linear & 127;
      bf16x8 v = *(const bf16x8*)(T + dd * 128 + (ts ^ ((dd & 7) << 4)));
      char* dstb = (char*)Vtg + (((size_t)(b * NH + h) * HD + dd) * S_LEN + s0) * 2 + ts;
      *(bf16x8*)dstb = v;
    }
  }
}

// ---------------- flash attention v3: swapped QK^T, P-in-registers, no LDS roundtrip ----
// grid 1024 = 32 bh * 32 qtiles(64 rows); waves: qo=wave>>1 (32 rows), kh=wave&1 (16 k-tiles)
__global__ __launch_bounds__(256) void attn_kernel(
    const unsigned short* __restrict__ Qg, const unsigned short* __restrict__ Kg,
    const unsigned short* __restrict__ Vtg, const float* __restrict__ biasg,
    unsigned short* __restrict__ aout) {
  __shared__ __align__(16) char shbuf[16640];   // merge[2][32][64]f32 + lml[64]f32
  __shared__ float biasl[2112];

  int bid = blockIdx.x;
  int swz = (bid & 7) * 128 + (bid >> 3);       // bijective (1024 % 8 == 0)
  int bh = swz >> 5;
  int qt = swz & 31;
  int b = bh >> 4, h = bh & 15;
  int qbase = qt * 64;
  const int tid = threadIdx.x, lane = tid & 63, wave = tid >> 6;
  const int lg = lane >> 4, li = lane & 15;
  const int qo = wave >> 1, kh = wave & 1;
  const int qsub = qo * 32;

  const char* Kbh = (const char*)Kg + (size_t)bh * S_LEN * HD * 2;
  const char* Vbh = (const char*)Vtg + (size_t)bh * HD * S_LEN * 2;
  const char* Qbh = (const char*)Qg + (size_t)bh * S_LEN * HD * 2;

  // bias strip: biasl[i] = biasg[h][i + 1984 - qbase], i in [0, 2111)
  for (int i = tid; i < 2112; i += 256)
    biasl[i] = (i < 2111) ? biasg[h * 4096 + i + 1984 - qbase] : 0.f;

  bf16x8 qf[2][2];
#pragma unroll
  for (int m = 0; m < 2; ++m)
#pragma unroll
    for (int kk = 0; kk < 2; ++kk)
      qf[m][kk] = *(const bf16x8*)(Qbh + (size_t)(qbase + qsub + m * 16 + li) * 128 + kk * 64 + lg * 16);

  f32x4 Oa[2][4];
  float lsum[2] = {0.f, 0.f};
#pragma unroll
  for (int m = 0; m < 2; ++m)
#pragma unroll
    for (int dt = 0; dt < 4; ++dt) Oa[m][dt] = (f32x4){0.f, 0.f, 0.f, 0.f};

  __syncthreads();

  for (int t = 0; t < 16; ++t) {
    int kt = kh * 16 + t;
    const char* Kt = Kbh + (size_t)kt * 64 * 128;

    // ---- QK^T swapped: sc[m][nt][r] = S[q = li][k = kt*64 + nt*16 + lg*4 + r] ----
    f32x4 sc[2][4];
#pragma unroll
    for (int m = 0; m < 2; ++m)
#pragma unroll
      for (int nt = 0; nt < 4; ++nt) sc[m][nt] = (f32x4){0.f, 0.f, 0.f, 0.f};
#pragma unroll
    for (int kk = 0; kk < 2; ++kk) {
      bf16x8 kf[4];
#pragma unroll
      for (int nt = 0; nt < 4; ++nt)
        kf[nt] = *(const bf16x8*)(Kt + (nt * 16 + li) * 128 + kk * 64 + lg * 16);
#pragma unroll
      for (int nt = 0; nt < 4; ++nt)
#pragma unroll
        for (int m = 0; m < 2; ++m)
          sc[m][nt] = __builtin_amdgcn_mfma_f32_16x16x32_bf16(kf[nt], qf[m][kk], sc[m][nt], 0, 0, 0);
    }

    // ---- V loads issued early (independent of softmax; hide L2 latency under it) ----
    // vf slots 0..3 <- Vt[d][k0 + lg*4 + 0..3], slots 4..7 <- Vt[d][k0 + 16 + lg*4 + 0..3]
    uint2 va[2][4], vb[2][4];
#pragma unroll
    for (int kk2 = 0; kk2 < 2; ++kk2)
#pragma unroll
      for (int dt = 0; dt < 4; ++dt) {
        const char* vp = Vbh + (size_t)(dt * 16 + li) * 4096 + kt * 128 + kk2 * 64 + lg * 8;
        va[kk2][dt] = *(const uint2*)vp;
        vb[kk2][dt] = *(const uint2*)(vp + 32);
      }

    // ---- softmax (unnormalized, lane-local): p = exp2(s + bias), pack to bf16 ----
    unsigned upk[2][4][2];
#pragma unroll
    for (int m = 0; m < 2; ++m) {
      int bb = kt * 64 + lg * 4 + 63 - (qsub + m * 16) - li;
#pragma unroll
      for (int nt = 0; nt < 4; ++nt) {
        float p0 = exp2f(sc[m][nt][0] + biasl[bb + nt * 16 + 0]);
        float p1 = exp2f(sc[m][nt][1] + biasl[bb + nt * 16 + 1]);
        float p2 = exp2f(sc[m][nt][2] + biasl[bb + nt * 16 + 2]);
        float p3 = exp2f(sc[m][nt][3] + biasl[bb + nt * 16 + 3]);
        lsum[m] += (p0 + p1) + (p2 + p3);
        upk[m][nt][0] = pkbf(p0, p1);
        upk[m][nt][1] = pkbf(p2, p3);
      }
    }

    // ---- PV: O[q = m*16+lg*4+r][d = dt*16+li] ----
#pragma unroll
    for (int kk2 = 0; kk2 < 2; ++kk2) {
      bf16x8 pa[2];
#pragma unroll
      for (int m = 0; m < 2; ++m) {
        u32x4 w = {upk[m][2 * kk2][0], upk[m][2 * kk2][1],
                   upk[m][2 * kk2 + 1][0], upk[m][2 * kk2 + 1][1]};
        pa[m] = __builtin_bit_cast(bf16x8, w);
      }
#pragma unroll
      for (int dt = 0; dt < 4; ++dt) {
        u32x4 w = {va[kk2][dt].x, va[kk2][dt].y, vb[kk2][dt].x, vb[kk2][dt].y};
        bf16x8 vf = __builtin_bit_cast(bf16x8, w);
#pragma unroll
        for (int m = 0; m < 2; ++m)
          Oa[m][dt] = __builtin_amdgcn_mfma_f32_16x16x32_bf16(pa[m], vf, Oa[m][dt], 0, 0, 0);
      }
    }
  }

  // ---- l reduce over lg-group (lanes li, li+16, li+32, li+48) ----
#pragma unroll
  for (int m = 0; m < 2; ++m) {
    lsum[m] += __shfl_xor(lsum[m], 16, 64);
    lsum[m] += __shfl_xor(lsum[m], 32, 64);
  }
  // fetch l for this lane's OUTPUT rows q = m*16 + lg*4 + r
  float lq[2][4];
#pragma unroll
  for (int m = 0; m < 2; ++m)
#pragma unroll
    for (int r = 0; r < 4; ++r)
      lq[m][r] = __shfl(lsum[m], lg * 4 + r, 64);

  // ---- merge the two k-halves (pure addition) ----
  __syncthreads();
  float* mo = (float*)shbuf;              // [2][32][64]
  float* lml = (float*)(shbuf + 16384);   // [64]
  if (kh == 1) {
#pragma unroll
    for (int m = 0; m < 2; ++m)
#pragma unroll
      for (int dt = 0; dt < 4; ++dt)
#pragma unroll
        for (int r = 0; r < 4; ++r)
          mo[(qo * 32 + m * 16 + lg * 4 + r) * 64 + dt * 16 + li] = Oa[m][dt][r];
    if (li == 0)
#pragma unroll
      for (int m = 0; m < 2; ++m)
#pragma unroll
        for (int r = 0; r < 4; ++r)
          lml[qo * 32 + m * 16 + lg * 4 + r] = lq[m][r];
  }
  __syncthreads();
  if (kh == 0) {
#pragma unroll
    for (int m = 0; m < 2; ++m) {
      float inv[4];
#pragma unroll
      for (int r = 0; r < 4; ++r)
        inv[r] = 1.0f / (lq[m][r] + lml[qo * 32 + m * 16 + lg * 4 + r]);
#pragma unroll
      for (int dt = 0; dt < 4; ++dt)
#pragma unroll
        for (int r = 0; r < 4; ++r) {
          float o = Oa[m][dt][r] + mo[(qo * 32 + m * 16 + lg * 4 + r) * 64 + dt * 16 + li];
          int srow = qbase + qsub + m * 16 + lg * 4 + r;
          aout[((size_t)b * S_LEN + srow) * DMODEL + h * HD + dt * 16 + li] = f2bf(o * inv[r]);
        }
    }
  }
}

// ---------------- O projection ----------------
__global__ __launch_bounds__(256) void oproj_gemm_kernel(
    const unsigned short* __restrict__ ab, const unsigned short* __restrict__ ob,
    float* __restrict__ out) {
  __shared__ __align__(16) char smem[32768];
  char* As = smem;
  char* Bs = smem + 16384;
  int bid = blockIdx.x;
  int swz = (bid & 7) * 32 + (bid >> 3);
  int bm = swz >> 3, bn = swz & 7;
  const int tid = threadIdx.x, lane = tid & 63, wave = tid >> 6;
  const int wr = wave >> 1, wc = wave & 1, lg = lane >> 4, li = lane & 15;
  const char* Ag = (const char*)ab;
  const char* Bg = (const char*)ob;

  f32x4 acc[4][4];
#pragma unroll
  for (int i = 0; i < 4; ++i)
#pragma unroll
    for (int j = 0; j < 4; ++j) acc[i][j] = (f32x4){0.f, 0.f, 0.f, 0.f};

  auto stage = [&](int buf, int kt) {
#pragma unroll
    for (int r = 0; r < 2; ++r) {
      int c = wave * 2 + r;
      int linear = c * 1024 + lane * 16;
      int row = linear >> 6;
      int cb = (linear & 63) ^ ((row & 3) << 4);
      async16(As + buf * 8192 + c * 1024,
              Ag + (size_t)(bm * 128 + row) * 2048 + kt * 64 + cb);
      async16(Bs + buf * 8192 + c * 1024,
              Bg + (size_t)(bn * 128 + row) * 2048 + kt * 64 + cb);
    }
  };

  stage(0, 0);
  __syncthreads();
  for (int kt = 0; kt < 32; ++kt) {
    int cur = kt & 1;
    if (kt < 31) stage(cur ^ 1, kt + 1);
    const char* Ab = As + cur * 8192;
    const char* Bb = Bs + cur * 8192;
    bf16x8 af[4], bfr[4];
#pragma unroll
    for (int i = 0; i < 4; ++i) {
      int ra = wr * 64 + i * 16 + li;
      af[i] = *(const bf16x8*)(Ab + ra * 64 + ((lg * 16) ^ ((ra & 3) << 4)));
      int rb = wc * 64 + i * 16 + li;
      bfr[i] = *(const bf16x8*)(Bb + rb * 64 + ((lg * 16) ^ ((rb & 3) << 4)));
    }
#pragma unroll
    for (int i = 0; i < 4; ++i)
#pragma unroll
      for (int j = 0; j < 4; ++j)
        acc[i][j] = __builtin_amdgcn_mfma_f32_16x16x32_bf16(af[i], bfr[j], acc[i][j], 0, 0, 0);
    __syncthreads();
  }

#pragma unroll
  for (int i = 0; i < 4; ++i)
#pragma unroll
    for (int j = 0; j < 4; ++j)
#pragma unroll
      for (int r = 0; r < 4; ++r) {
        int mr = bm * 128 + wr * 64 + i * 16 + lg * 4 + r;
        int n = bn * 128 + wc * 64 + j * 16 + li;
        out[(size_t)mr * DMODEL + n] = acc[i][j][r];
      }
}

// ---------------- host ----------------
extern "C" void kernel_launch(void* const* d_in, const int* in_sizes, int n_in,
                              void* d_out, int out_size, void* d_ws, size_t ws_size,
                              hipStream_t stream) {
  const float* x     = (const float*)d_in[0];
  const float* emb   = (const float*)d_in[1];
  const float* qkv_w = (const float*)d_in[2];
  const float* o_w   = (const float*)d_in[3];
  char* ws = (char*)d_ws;
  unsigned short* xb = (unsigned short*)(ws);
  unsigned short* wb = (unsigned short*)(ws + 8388608);
  unsigned short* ob = (unsigned short*)(ws + 14680064);
  unsigned short* Qg = (unsigned short*)(ws + 16777216);
  unsigned short* Kg = (unsigned short*)(ws + 25165824);
  unsigned short* Vt = (unsigned short*)(ws + 33554432);
  unsigned short* ab = (unsigned short*)(ws + 41943040);
  float* biasg       = (float*)(ws + 50331648);
  float* out = (float*)d_out;

  prep_kernel<<<8208, 256, 0, stream>>>(x, emb, qkv_w, o_w, xb, wb, ob, biasg);
  qkv_gemm_kernel<<<768, 256, 0, stream>>>(xb, wb, Qg, Kg, Vt);
  attn_kernel<<<1024, 256, 0, stream>>>(Qg, Kg, Vt, biasg, ab);
  oproj_gemm_kernel<<<256, 256, 0, stream>>>(ab, ob, out);
}

// Round 12
// 215.648 us; speedup vs baseline: 1.4511x; 1.4511x over previous
//
#include <hip/hip_runtime.h>

#define S_LEN 2048
#define NH 16
#define HD 64
#define DMODEL 1024

typedef __attribute__((ext_vector_type(8))) short bf16x8;
typedef __attribute__((ext_vector_type(4))) float f32x4;
typedef __attribute__((ext_vector_type(4))) unsigned int u32x4;

__device__ inline unsigned short f2bf(float f) {
  union { float f; unsigned u; } v; v.f = f;
  unsigned r = v.u + 0x7FFFu + ((v.u >> 16) & 1u);
  return (unsigned short)(r >> 16);
}

__device__ inline void async16(void* lds, const void* g) {
  __builtin_amdgcn_global_load_lds((__attribute__((address_space(1))) void*)(g),
                                   (__attribute__((address_space(3))) void*)(lds),
                                   16, 0, 0);
}

// pack two positive f32 to bf16 pair (round-half-up), low word = a
__device__ inline unsigned pkbf(float a, float b) {
  unsigned ua = __float_as_uint(a) + 0x8000u;
  unsigned ub = __float_as_uint(b) + 0x8000u;
  return (ua >> 16) | (ub & 0xFFFF0000u);
}

// ---------------- prep: fp32->bf16 casts + bias table (exp2-domain) ----------------
__global__ __launch_bounds__(256) void prep_kernel(
    const float* __restrict__ x, const float* __restrict__ emb,
    const float* __restrict__ qkv_w, const float* __restrict__ o_w,
    unsigned short* __restrict__ xb, unsigned short* __restrict__ wb,
    unsigned short* __restrict__ ob, float* __restrict__ biasg) {
  if (blockIdx.x >= 8192) {
    int h = blockIdx.x - 8192;
    for (int i = threadIdx.x; i < 4095; i += 256) {
      int rel = i - 2047;                       // rel = k - q
      int a = rel < 0 ? -rel : rel;
      int bucket;
      if (a < 8) bucket = a;
      else bucket = 8 + (a >= 12) + (a >= 16) + (a >= 23) + (a >= 32) +
                        (a >= 46) + (a >= 64) + (a >= 91);
      if (rel > 0) bucket += 16;
      biasg[h * 4096 + i] = emb[bucket * NH + h] * 1.4426950408889634f;
    }
    return;
  }
  const int NX = 2 * S_LEN * DMODEL / 4;
  const int NW = 3 * NH * HD * DMODEL / 4;
  int j = blockIdx.x * 256 + threadIdx.x;
  const float* s; unsigned short* d;
  if (j < NX)            { s = x;     d = xb; }
  else if (j < NX + NW)  { j -= NX;      s = qkv_w; d = wb; }
  else                   { j -= NX + NW; s = o_w;   d = ob; }
  float4 v = ((const float4*)s)[j];
  ushort4 p;
  p.x = f2bf(v.x); p.y = f2bf(v.y); p.z = f2bf(v.z); p.w = f2bf(v.w);
  ((ushort4*)d)[j] = p;
}

// ---------------- QKV GEMM: [4096,1024]bf16 @ [3072,1024]^T -> Q,K,Vt ----------------
__global__ __launch_bounds__(256) void qkv_gemm_kernel(
    const unsigned short* __restrict__ xb, const unsigned short* __restrict__ wb,
    unsigned short* __restrict__ Qg, unsigned short* __restrict__ Kg,
    unsigned short* __restrict__ Vtg) {
  __shared__ __align__(16) char smem[32768];
  char* As = smem;
  char* Bs = smem + 16384;
  int bid = blockIdx.x;
  int swz = (bid & 7) * 96 + (bid >> 3);
  int bm = swz / 24, bn = swz % 24;
  const int tid = threadIdx.x, lane = tid & 63, wave = tid >> 6;
  const int wr = wave >> 1, wc = wave & 1, lg = lane >> 4, li = lane & 15;
  const char* Ag = (const char*)xb;
  const char* Bg = (const char*)wb;

  f32x4 acc[4][4];
#pragma unroll
  for (int i = 0; i < 4; ++i)
#pragma unroll
    for (int j = 0; j < 4; ++j) acc[i][j] = (f32x4){0.f, 0.f, 0.f, 0.f};

  auto stage = [&](int buf, int kt) {
#pragma unroll
    for (int r = 0; r < 2; ++r) {
      int c = wave * 2 + r;
      int linear = c * 1024 + lane * 16;
      int row = linear >> 6;
      int cb = (linear & 63) ^ ((row & 3) << 4);
      async16(As + buf * 8192 + c * 1024,
              Ag + (size_t)(bm * 128 + row) * 2048 + kt * 64 + cb);
      async16(Bs + buf * 8192 + c * 1024,
              Bg + (size_t)(bn * 128 + row) * 2048 + kt * 64 + cb);
    }
  };

  stage(0, 0);
  __syncthreads();
  for (int kt = 0; kt < 32; ++kt) {
    int cur = kt & 1;
    if (kt < 31) stage(cur ^ 1, kt + 1);
    const char* Ab = As + cur * 8192;
    const char* Bb = Bs + cur * 8192;
    bf16x8 af[4], bfr[4];
#pragma unroll
    for (int i = 0; i < 4; ++i) {
      int ra = wr * 64 + i * 16 + li;
      af[i] = *(const bf16x8*)(Ab + ra * 64 + ((lg * 16) ^ ((ra & 3) << 4)));
      int rb = wc * 64 + i * 16 + li;
      bfr[i] = *(const bf16x8*)(Bb + rb * 64 + ((lg * 16) ^ ((rb & 3) << 4)));
    }
#pragma unroll
    for (int i = 0; i < 4; ++i)
#pragma unroll
      for (int j = 0; j < 4; ++j)
        acc[i][j] = __builtin_amdgcn_mfma_f32_16x16x32_bf16(af[i], bfr[j], acc[i][j], 0, 0, 0);
    __syncthreads();
  }

  int n0 = bn * 128 + wc * 64;
  int which = n0 >> 10;
  int h = (n0 >> 6) & 15;
  if (which < 2) {
    unsigned short* dst = (which == 0) ? Qg : Kg;
    float scl = (which == 0) ? 0.18033688011112042f : 1.0f;
#pragma unroll
    for (int i = 0; i < 4; ++i)
#pragma unroll
      for (int j = 0; j < 4; ++j)
#pragma unroll
        for (int r = 0; r < 4; ++r) {
          int mr = bm * 128 + wr * 64 + i * 16 + lg * 4 + r;
          int b = mr >> 11, sIdx = mr & 2047;
          int d = j * 16 + li;
          dst[(((size_t)(b * NH + h)) * S_LEN + sIdx) * HD + d] = f2bf(acc[i][j][r] * scl);
        }
  } else {
    char* T = smem + wave * 8192;
#pragma unroll
    for (int i = 0; i < 4; ++i)
#pragma unroll
      for (int j = 0; j < 4; ++j)
#pragma unroll
        for (int r = 0; r < 4; ++r) {
          int sl = i * 16 + lg * 4 + r;
          int dd = j * 16 + li;
          *(unsigned short*)(T + dd * 128 + ((sl * 2) ^ ((dd & 7) << 4))) = f2bf(acc[i][j][r]);
        }
    int m0 = bm * 128 + wr * 64;
    int b = m0 >> 11, s0 = m0 & 2047;
#pragma unroll
    for (int r2 = 0; r2 < 8; ++r2) {
      int linear = r2 * 1024 + lane * 16;
      int dd = linear >> 7;
      int ts = linear & 127;
      bf16x8 v = *(const bf16x8*)(T + dd * 128 + (ts ^ ((dd & 7) << 4)));
      char* dstb = (char*)Vtg + (((size_t)(b * NH + h) * HD + dd) * S_LEN + s0) * 2 + ts;
      *(bf16x8*)dstb = v;
    }
  }
}

// ---------------- flash attention v4: LDS-staged K/V (coalesced) + P-in-registers ----
// grid 512 = 32 bh * 16 qtiles(128 rows); 4 waves, each owns 32 q-rows; shared k-tiles
__global__ __launch_bounds__(256) void attn_kernel(
    const unsigned short* __restrict__ Qg, const unsigned short* __restrict__ Kg,
    const unsigned short* __restrict__ Vtg, const float* __restrict__ biasg,
    unsigned short* __restrict__ aout) {
  __shared__ __align__(16) char Kl[2][8192];
  __shared__ __align__(16) char Vl[2][8192];
  __shared__ float biasl[2176];

  int bid = blockIdx.x;
  int swz = (bid & 7) * 64 + (bid >> 3);       // bijective (512 % 8 == 0)
  int bh = swz >> 4;
  int qt = swz & 15;
  int b = bh >> 4, h = bh & 15;
  int qbase = qt * 128;
  const int tid = threadIdx.x, lane = tid & 63, wave = tid >> 6;
  const int lg = lane >> 4, li = lane & 15;
  const int qw = wave * 32;

  const char* Kbh = (const char*)Kg + (size_t)bh * S_LEN * HD * 2;
  const char* Vbh = (const char*)Vtg + (size_t)bh * HD * S_LEN * 2;
  const char* Qbh = (const char*)Qg + (size_t)bh * S_LEN * HD * 2;

  // bias strip: biasl[i] = biasg[h][i + 1920 - qbase], i in [0, 2175)
  for (int i = tid; i < 2176; i += 256)
    biasl[i] = (i < 2175) ? biasg[h * 4096 + i + 1920 - qbase] : 0.f;

  // Q frags: q = qbase + qw + m*16 + li (q is the B-operand col in swapped QK^T)
  bf16x8 qf[2][2];
#pragma unroll
  for (int m = 0; m < 2; ++m)
#pragma unroll
    for (int kk = 0; kk < 2; ++kk)
      qf[m][kk] = *(const bf16x8*)(Qbh + (size_t)(qbase + qw + m * 16 + li) * 128 + kk * 64 + lg * 16);

  f32x4 Oa[2][4];
  float lsum[2] = {0.f, 0.f};
#pragma unroll
  for (int m = 0; m < 2; ++m)
#pragma unroll
    for (int dt = 0; dt < 4; ++dt) Oa[m][dt] = (f32x4){0.f, 0.f, 0.f, 0.f};

  // coalesced stage: K tile (64 k-rows x 128B) + Vt tile (64 d-rows x 128B slice),
  // linear LDS dest + inverse-swizzled global source (rule: both-sides-or-neither)
  auto stage = [&](int buf, int kt) {
#pragma unroll
    for (int r = 0; r < 2; ++r) {
      int c = wave * 2 + r;
      int linear = c * 1024 + lane * 16;
      int row = linear >> 7;                        // 0..63
      int sb = (linear & 127) ^ ((row & 7) << 4);   // pre-swizzled source byte
      async16(Kl[buf] + c * 1024, Kbh + (size_t)(kt * 64 + row) * 128 + sb);
      async16(Vl[buf] + c * 1024, Vbh + (size_t)row * 4096 + kt * 128 + sb);
    }
  };

  stage(0, 0);
  __syncthreads();

  for (int t = 0; t < 32; ++t) {
    int cur = t & 1;
    if (t < 31) stage(cur ^ 1, t + 1);

    // ---- QK^T swapped: sc[m][nt][r] = S[q = li][k = t*64 + nt*16 + lg*4 + r] ----
    f32x4 sc[2][4];
#pragma unroll
    for (int m = 0; m < 2; ++m)
#pragma unroll
      for (int nt = 0; nt < 4; ++nt) sc[m][nt] = (f32x4){0.f, 0.f, 0.f, 0.f};
#pragma unroll
    for (int kk = 0; kk < 2; ++kk) {
      bf16x8 kf[4];
#pragma unroll
      for (int nt = 0; nt < 4; ++nt) {
        int row = nt * 16 + li;
        kf[nt] = *(const bf16x8*)(Kl[cur] + row * 128 +
                                  ((kk * 64 + lg * 16) ^ ((row & 7) << 4)));
      }
#pragma unroll
      for (int nt = 0; nt < 4; ++nt)
#pragma unroll
        for (int m = 0; m < 2; ++m)
          sc[m][nt] = __builtin_amdgcn_mfma_f32_16x16x32_bf16(kf[nt], qf[m][kk], sc[m][nt], 0, 0, 0);
    }

    // ---- softmax (unnormalized, lane-local): p = exp2(s + bias), pack to bf16 ----
    unsigned upk[2][4][2];
#pragma unroll
    for (int m = 0; m < 2; ++m) {
      int bb = t * 64 + lg * 4 + 127 - qw - m * 16 - li;
#pragma unroll
      for (int nt = 0; nt < 4; ++nt) {
        float p0 = exp2f(sc[m][nt][0] + biasl[bb + nt * 16 + 0]);
        float p1 = exp2f(sc[m][nt][1] + biasl[bb + nt * 16 + 1]);
        float p2 = exp2f(sc[m][nt][2] + biasl[bb + nt * 16 + 2]);
        float p3 = exp2f(sc[m][nt][3] + biasl[bb + nt * 16 + 3]);
        lsum[m] += (p0 + p1) + (p2 + p3);
        upk[m][nt][0] = pkbf(p0, p1);
        upk[m][nt][1] = pkbf(p2, p3);
      }
    }

    // ---- PV from LDS: O[q = m*16+lg*4+r][d = dt*16+li] ----
#pragma unroll
    for (int kk2 = 0; kk2 < 2; ++kk2) {
      bf16x8 pa[2];
#pragma unroll
      for (int m = 0; m < 2; ++m) {
        u32x4 w = {upk[m][2 * kk2][0], upk[m][2 * kk2][1],
                   upk[m][2 * kk2 + 1][0], upk[m][2 * kk2 + 1][1]};
        pa[m] = __builtin_bit_cast(bf16x8, w);
      }
#pragma unroll
      for (int dt = 0; dt < 4; ++dt) {
        int row = dt * 16 + li;
        const char* base = Vl[cur] + row * 128;
        int s0 = (kk2 * 64 + lg * 8) ^ ((row & 7) << 4);
        int s1 = (kk2 * 64 + 32 + lg * 8) ^ ((row & 7) << 4);
        uint2 va = *(const uint2*)(base + s0);
        uint2 vb = *(const uint2*)(base + s1);
        u32x4 w = {va.x, va.y, vb.x, vb.y};
        bf16x8 vf = __builtin_bit_cast(bf16x8, w);
#pragma unroll
        for (int m = 0; m < 2; ++m)
          Oa[m][dt] = __builtin_amdgcn_mfma_f32_16x16x32_bf16(pa[m], vf, Oa[m][dt], 0, 0, 0);
      }
    }
    __syncthreads();
  }

  // ---- l reduce over lg-group (lanes li, li+16, li+32, li+48) ----
#pragma unroll
  for (int m = 0; m < 2; ++m) {
    lsum[m] += __shfl_xor(lsum[m], 16, 64);
    lsum[m] += __shfl_xor(lsum[m], 32, 64);
  }
  // fetch l for this lane's OUTPUT rows q = m*16 + lg*4 + r
  float lq[2][4];
#pragma unroll
  for (int m = 0; m < 2; ++m)
#pragma unroll
    for (int r = 0; r < 4; ++r)
      lq[m][r] = __shfl(lsum[m], lg * 4 + r, 64);

  // ---- normalize and store (no split-k merge needed) ----
#pragma unroll
  for (int m = 0; m < 2; ++m) {
    float inv[4];
#pragma unroll
    for (int r = 0; r < 4; ++r) inv[r] = 1.0f / lq[m][r];
#pragma unroll
    for (int dt = 0; dt < 4; ++dt)
#pragma unroll
      for (int r = 0; r < 4; ++r) {
        int srow = qbase + qw + m * 16 + lg * 4 + r;
        aout[((size_t)b * S_LEN + srow) * DMODEL + h * HD + dt * 16 + li] =
            f2bf(Oa[m][dt][r] * inv[r]);
      }
  }
}

// ---------------- O projection ----------------
__global__ __launch_bounds__(256) void oproj_gemm_kernel(
    const unsigned short* __restrict__ ab, const unsigned short* __restrict__ ob,
    float* __restrict__ out) {
  __shared__ __align__(16) char smem[32768];
  char* As = smem;
  char* Bs = smem + 16384;
  int bid = blockIdx.x;
  int swz = (bid & 7) * 32 + (bid >> 3);
  int bm = swz >> 3, bn = swz & 7;
  const int tid = threadIdx.x, lane = tid & 63, wave = tid >> 6;
  const int wr = wave >> 1, wc = wave & 1, lg = lane >> 4, li = lane & 15;
  const char* Ag = (const char*)ab;
  const char* Bg = (const char*)ob;

  f32x4 acc[4][4];
#pragma unroll
  for (int i = 0; i < 4; ++i)
#pragma unroll
    for (int j = 0; j < 4; ++j) acc[i][j] = (f32x4){0.f, 0.f, 0.f, 0.f};

  auto stage = [&](int buf, int kt) {
#pragma unroll
    for (int r = 0; r < 2; ++r) {
      int c = wave * 2 + r;
      int linear = c * 1024 + lane * 16;
      int row = linear >> 6;
      int cb = (linear & 63) ^ ((row & 3) << 4);
      async16(As + buf * 8192 + c * 1024,
              Ag + (size_t)(bm * 128 + row) * 2048 + kt * 64 + cb);
      async16(Bs + buf * 8192 + c * 1024,
              Bg + (size_t)(bn * 128 + row) * 2048 + kt * 64 + cb);
    }
  };

  stage(0, 0);
  __syncthreads();
  for (int kt = 0; kt < 32; ++kt) {
    int cur = kt & 1;
    if (kt < 31) stage(cur ^ 1, kt + 1);
    const char* Ab = As + cur * 8192;
    const char* Bb = Bs + cur * 8192;
    bf16x8 af[4], bfr[4];
#pragma unroll
    for (int i = 0; i < 4; ++i) {
      int ra = wr * 64 + i * 16 + li;
      af[i] = *(const bf16x8*)(Ab + ra * 64 + ((lg * 16) ^ ((ra & 3) << 4)));
      int rb = wc * 64 + i * 16 + li;
      bfr[i] = *(const bf16x8*)(Bb + rb * 64 + ((lg * 16) ^ ((rb & 3) << 4)));
    }
#pragma unroll
    for (int i = 0; i < 4; ++i)
#pragma unroll
      for (int j = 0; j < 4; ++j)
        acc[i][j] = __builtin_amdgcn_mfma_f32_16x16x32_bf16(af[i], bfr[j], acc[i][j], 0, 0, 0);
    __syncthreads();
  }

#pragma unroll
  for (int i = 0; i < 4; ++i)
#pragma unroll
    for (int j = 0; j < 4; ++j)
#pragma unroll
      for (int r = 0; r < 4; ++r) {
        int mr = bm * 128 + wr * 64 + i * 16 + lg * 4 + r;
        int n = bn * 128 + wc * 64 + j * 16 + li;
        out[(size_t)mr * DMODEL + n] = acc[i][j][r];
      }
}

// ---------------- host ----------------
extern "C" void kernel_launch(void* const* d_in, const int* in_sizes, int n_in,
                              void* d_out, int out_size, void* d_ws, size_t ws_size,
                              hipStream_t stream) {
  const float* x     = (const float*)d_in[0];
  const float* emb   = (const float*)d_in[1];
  const float* qkv_w = (const float*)d_in[2];
  const float* o_w   = (const float*)d_in[3];
  char* ws = (char*)d_ws;
  unsigned short* xb = (unsigned short*)(ws);
  unsigned short* wb = (unsigned short*)(ws + 8388608);
  unsigned short* ob = (unsigned short*)(ws + 14680064);
  unsigned short* Qg = (unsigned short*)(ws + 16777216);
  unsigned short* Kg = (unsigned short*)(ws + 25165824);
  unsigned short* Vt = (unsigned short*)(ws + 33554432);
  unsigned short* ab = (unsigned short*)(ws + 41943040);
  float* biasg       = (float*)(ws + 50331648);
  float* out = (float*)d_out;

  prep_kernel<<<8208, 256, 0, stream>>>(x, emb, qkv_w, o_w, xb, wb, ob, biasg);
  qkv_gemm_kernel<<<768, 256, 0, stream>>>(xb, wb, Qg, Kg, Vt);
  attn_kernel<<<512, 256, 0, stream>>>(Qg, Kg, Vt, biasg, ab);
  oproj_gemm_kernel<<<256, 256, 0, stream>>>(ab, ob, out);
}